// Round 1
// 309.938 us; speedup vs baseline: 1.0044x; 1.0044x over previous
//
#include <hip/hip_runtime.h>

typedef __attribute__((ext_vector_type(8))) short bf16x8;
typedef __attribute__((ext_vector_type(4))) float floatx4;

static __device__ __forceinline__ float b2f(unsigned short u) {
  union { unsigned int i; float f; } v; v.i = ((unsigned int)u) << 16; return v.f;
}
static __device__ __forceinline__ unsigned short f2b(float f) {
  union { float f; unsigned int i; } v; v.f = f;
  unsigned int x = v.i;
  return (unsigned short)((x + 0x7fffu + ((x >> 16) & 1u)) >> 16);
}

#define GLDS(gp, lp) \
  __builtin_amdgcn_global_load_lds( \
      (const __attribute__((address_space(1))) unsigned int*)(gp), \
      (__attribute__((address_space(3))) unsigned int*)(lp), 16, 0, 0)

// XCD-aware swizzle for gemm_down (unchanged)
static __device__ __forceinline__ void swizzle_mn(int lin, int Mb, int Nb,
                                                  int& m_idx, int& n_idx) {
  if ((Mb & 7) == 0) {
    int xcd = lin & 7;
    int idx = lin >> 3;
    int nstrips = Mb >> 3;
    m_idx = (idx % nstrips) * 8 + xcd;
    n_idx = idx / nstrips;
  } else {
    m_idx = lin % Mb;
    n_idx = lin / Mb;
  }
}

// ---------------- fp32 -> bf16 elementwise convert ------------------------------
__global__ void cvt_f32_bf16(const float* __restrict__ src,
                             unsigned short* __restrict__ dst) {
  int i = (blockIdx.x * 256 + threadIdx.x) * 4;
  float4 v = *(const float4*)(src + i);
  ushort4 o;
  o.x = f2b(v.x); o.y = f2b(v.y); o.z = f2b(v.z); o.w = f2b(v.w);
  *(ushort4*)(dst + i) = o;
}

// ------------- weight convert+transpose: fp32 [K,N] -> bf16 [N,K] ---------------
__global__ void transpose_f32_bf16_2(const float* __restrict__ sA,
                                     unsigned short* __restrict__ dA, int nzA,
                                     const float* __restrict__ sB,
                                     unsigned short* __restrict__ dB,
                                     int K, int N) {
  __shared__ unsigned short tile[32][33];
  int z = blockIdx.z;
  const float* src;
  unsigned short* dst;
  if (z < nzA) { src = sA + (size_t)z * K * N; dst = dA + (size_t)z * K * N; }
  else { src = sB + (size_t)(z - nzA) * K * N; dst = dB + (size_t)(z - nzA) * K * N; }
  const int bx = blockIdx.x * 32;
  const int by = blockIdx.y * 32;
  const int tx = threadIdx.x, ty = threadIdx.y;
#pragma unroll
  for (int i = 0; i < 4; i++)
    tile[ty + i * 8][tx] = f2b(src[(size_t)(by + ty + i * 8) * N + bx + tx]);
  __syncthreads();
#pragma unroll
  for (int i = 0; i < 4; i++)
    dst[(size_t)(bx + ty + i * 8) * K + by + tx] = tile[tx][ty + i * 8];
}

__global__ void transpose3_1024(const float* __restrict__ s0,
                                const float* __restrict__ s1,
                                const float* __restrict__ s2,
                                unsigned short* __restrict__ d0,
                                unsigned short* __restrict__ d1,
                                unsigned short* __restrict__ d2) {
  __shared__ unsigned short tile[32][33];
  const float* src = (blockIdx.z == 0) ? s0 : (blockIdx.z == 1) ? s1 : s2;
  unsigned short* dst = (blockIdx.z == 0) ? d0 : (blockIdx.z == 1) ? d1 : d2;
  const int bx = blockIdx.x * 32;
  const int by = blockIdx.y * 32;
  const int tx = threadIdx.x, ty = threadIdx.y;
#pragma unroll
  for (int i = 0; i < 4; i++)
    tile[ty + i * 8][tx] = f2b(src[(size_t)(by + ty + i * 8) * 1024 + bx + tx]);
  __syncthreads();
#pragma unroll
  for (int i = 0; i < 4; i++)
    dst[(size_t)(bx + ty + i * 8) * 1024 + by + tx] = tile[tx][ty + i * 8];
}

// ---------------- router: fp32 softmax over 8 logits, zero 2 smallest -----------
__global__ void router_topk(const float* __restrict__ X,
                            const float* __restrict__ RW,
                            float* __restrict__ cw) {
  const int t = blockIdx.x;
  const int lane = threadIdx.x;  // 64
  float acc[8];
#pragma unroll
  for (int e = 0; e < 8; e++) acc[e] = 0.f;
  for (int d = lane; d < 1024; d += 64) {
    float xv = X[(size_t)t * 1024 + d];
    const float* r = RW + d * 8;
    float4 r0 = *(const float4*)r;
    float4 r1 = *(const float4*)(r + 4);
    acc[0] += xv * r0.x; acc[1] += xv * r0.y;
    acc[2] += xv * r0.z; acc[3] += xv * r0.w;
    acc[4] += xv * r1.x; acc[5] += xv * r1.y;
    acc[6] += xv * r1.z; acc[7] += xv * r1.w;
  }
#pragma unroll
  for (int m = 1; m < 64; m <<= 1) {
#pragma unroll
    for (int e = 0; e < 8; e++) acc[e] += __shfl_xor(acc[e], m);
  }
  if (lane == 0) {
    float mx = acc[0];
#pragma unroll
    for (int e = 1; e < 8; e++) mx = fmaxf(mx, acc[e]);
    float prob[8], s = 0.f;
#pragma unroll
    for (int e = 0; e < 8; e++) { prob[e] = expf(acc[e] - mx); s += prob[e]; }
    float inv = 1.f / s;
#pragma unroll
    for (int e = 0; e < 8; e++) prob[e] *= inv;
    int m1 = 0;
#pragma unroll
    for (int e = 1; e < 8; e++) if (prob[e] < prob[m1]) m1 = e;
    int m2 = -1;
#pragma unroll
    for (int e = 0; e < 8; e++)
      if (e != m1 && (m2 < 0 || prob[e] < prob[m2])) m2 = e;
#pragma unroll
    for (int e = 0; e < 8; e++)
      cw[(size_t)t * 8 + e] = (e == m1 || e == m2) ? 0.f : prob[e];
  }
}

// ------------- fused gate+up GEMM: H = cw * silu(X@Wg) * (X@Wu) -----------------
// m201-class schedule: BM=256, BN=128, BK=64, 8 waves (2Mx4N, wave 128x32 per
// matrix). Double-buffered 128KB LDS, 4 phases/K-tile, 2 GLDS staged per phase,
// counted vmcnt(6) (never 0 in main loop), XOR chunk-swizzle (^row&7) on
// pre-swizzled global source + ds_read addr, raw s_barrier, setprio on MFMA.
// Per K-tile issue order: I0=A-h0, I1=Bg, I2=Bu, I3=A-h1; phase p consumes the
// pair retired by its vmcnt(6).
#define VMCNT(N) asm volatile("s_waitcnt vmcnt(" #N ")" ::: "memory")
#define BARS() do { __builtin_amdgcn_s_barrier(); \
                    __builtin_amdgcn_sched_barrier(0); } while (0)

#define STG_I0(K, BS) do { \
  GLDS(a0 + (K),          sm + (BS) + wid * 512); \
  GLDS(a0 + (K) + 131072, sm + (BS) + 8192 + wid * 512); } while (0)
#define STG_I1(K, BS) do { \
  GLDS(bg0 + (K),        sm + (BS) + 16384 + wid * 1024); \
  GLDS(bg0 + (K) + 8192, sm + (BS) + 16384 + wid * 1024 + 512); } while (0)
#define STG_I2(K, BS) do { \
  GLDS(bu0 + (K),        sm + (BS) + 24576 + wid * 1024); \
  GLDS(bu0 + (K) + 8192, sm + (BS) + 24576 + wid * 1024 + 512); } while (0)
#define STG_I3(K, BS) do { \
  GLDS(a0 + (K) + 65536,  sm + (BS) + 4096 + wid * 512); \
  GLDS(a0 + (K) + 196608, sm + (BS) + 12288 + wid * 512); } while (0)

#define READ_A(DST, DB, H) do { _Pragma("unroll") \
  for (int mf = 0; mf < 4; ++mf) { \
    const int row_ = wm * 128 + (H) * 64 + mf * 16 + lr; \
    const int rb_ = (DB) + row_ * 64; const int rx_ = row_ & 7; \
    DST[mf][0] = *(const bf16x8*)(sm + rb_ + ((quad ^ rx_) << 3)); \
    DST[mf][1] = *(const bf16x8*)(sm + rb_ + (((4 + quad) ^ rx_) << 3)); \
  } } while (0)

#define READ_B(DST, DB, RG) do { _Pragma("unroll") \
  for (int nf = 0; nf < 2; ++nf) { \
    const int row_ = wn * 32 + nf * 16 + lr; \
    const int rb_ = (DB) + (RG) + row_ * 64; const int rx_ = row_ & 7; \
    DST[nf][0] = *(const bf16x8*)(sm + rb_ + ((quad ^ rx_) << 3)); \
    DST[nf][1] = *(const bf16x8*)(sm + rb_ + (((4 + quad) ^ rx_) << 3)); \
  } } while (0)

#define MM(ACC, AF, BF) do { \
  __builtin_amdgcn_s_setprio(1); \
  _Pragma("unroll") \
  for (int mf = 0; mf < 4; ++mf) { _Pragma("unroll") \
    for (int nf = 0; nf < 2; ++nf) { \
      ACC[mf][nf] = __builtin_amdgcn_mfma_f32_16x16x32_bf16( \
          AF[mf][0], BF[nf][0], ACC[mf][nf], 0, 0, 0); \
      ACC[mf][nf] = __builtin_amdgcn_mfma_f32_16x16x32_bf16( \
          AF[mf][1], BF[nf][1], ACC[mf][nf], 0, 0, 0); \
    } } \
  __builtin_amdgcn_s_setprio(0); } while (0)

__global__ __launch_bounds__(512, 2) void gemm_gu_fused(
    const unsigned short* __restrict__ X,
    const unsigned short* __restrict__ WgTe,
    const unsigned short* __restrict__ WgTs,
    const unsigned short* __restrict__ WuTe,
    const unsigned short* __restrict__ WuTs,
    unsigned short* __restrict__ H,
    const float* __restrict__ cw, int Mb) {
  // LDS per buffer (shorts): A [0,16384) 256x64 | Bg [16384,24576) 128x64 |
  // Bu [24576,32768) 128x64.  Two buffers, 128 KiB total -> 1 block/CU.
  __shared__ __align__(16) unsigned short sm[65536];
  const int tid = threadIdx.x;
  const int wid = tid >> 6, lane = tid & 63;
  const int lr = lane & 15, quad = lane >> 4;
  const int wm = wid >> 2, wn = wid & 3;

  // grid swizzle: n fastest within an XCD's m-strips
  int m_idx, n_idx;
  {
    int lin = blockIdx.x;
    if ((Mb & 7) == 0) {
      int xcd = lin & 7, idx = lin >> 3;
      n_idx = idx % 40;
      m_idx = (idx / 40) * 8 + xcd;
    } else {
      m_idx = lin % Mb;
      n_idx = lin / Mb;
    }
  }
  const int m0 = m_idx * 256;
  const int n0 = n_idx * 128;

  const unsigned short *Bg, *Bu;
  int eidx = -1;
  if (n0 < 4096) {
    eidx = n0 >> 9;
    size_t off = ((size_t)eidx * 512 + (n0 & 511)) * 1024;
    Bg = WgTe + off; Bu = WuTe + off;
  } else {
    size_t off = (size_t)(n0 - 4096) * 1024;
    Bg = WgTs + off; Bu = WuTs + off;
  }

  // per-lane pre-swizzled global source bases (chunk ^= row&7 baked in):
  // lane l -> row-in-octet l>>3, stored chunk l&7 holds global chunk (l&7)^(l>>3)
  const int grow8 = lane >> 3;
  const int gcol = ((lane & 7) ^ grow8) << 3;
  const unsigned short* a0 =
      X + (size_t)(m0 + wid * 8 + grow8) * 1024 + gcol;
  const unsigned short* bg0 =
      Bg + (size_t)(wid * 16 + grow8) * 1024 + gcol;
  const unsigned short* bu0 =
      Bu + (size_t)(wid * 16 + grow8) * 1024 + gcol;

  floatx4 gg[2][4][2], uu[2][4][2];
#pragma unroll
  for (int h = 0; h < 2; h++)
#pragma unroll
    for (int mf = 0; mf < 4; mf++)
#pragma unroll
      for (int nf = 0; nf < 2; nf++) {
        gg[h][mf][nf] = (floatx4)0.f;
        uu[h][mf][nf] = (floatx4)0.f;
      }

  bf16x8 fA0[4][2], fA1[4][2], fBg[2][2], fBu[2][2];

  // prologue: tile 0 into buffer 0
  STG_I0(0, 0); STG_I1(0, 0); STG_I2(0, 0); STG_I3(0, 0);

  // steady state: tiles 0..14, staging t+1 while computing t
  for (int t = 0; t < 15; ++t) {
    const int db = (t & 1) << 15;        // read buffer (shorts)
    const int nb = 32768 - db;           // stage buffer
    const int kn = (t + 1) * 64;         // next K offset (elements)
    // phase 0: gate x A-h0
    STG_I0(kn, nb);
    VMCNT(6); BARS();
    READ_A(fA0, db, 0);
    READ_B(fBg, db, 16384);
    MM(gg[0], fA0, fBg);
    // phase 1: up x A-h0
    STG_I1(kn, nb);
    VMCNT(6); BARS();
    READ_B(fBu, db, 24576);
    MM(uu[0], fA0, fBu);
    // phase 2: gate x A-h1
    STG_I2(kn, nb);
    VMCNT(6); BARS();
    READ_A(fA1, db, 1);
    MM(gg[1], fA1, fBg);
    // phase 3: up x A-h1 (no new data; barrier releases buffer overwrite)
    STG_I3(kn, nb);
    BARS();
    MM(uu[1], fA1, fBu);
  }
  // peeled last tile (t=15, buffer 1): drain waits 4/2/0
  {
    const int db = 32768;
    VMCNT(4); BARS();
    READ_A(fA0, db, 0);
    READ_B(fBg, db, 16384);
    MM(gg[0], fA0, fBg);
    VMCNT(2); BARS();
    READ_B(fBu, db, 24576);
    MM(uu[0], fA0, fBu);
    VMCNT(0); BARS();
    READ_A(fA1, db, 1);
    MM(gg[1], fA1, fBg);
    MM(uu[1], fA1, fBu);
  }

  // epilogue: silu(g)*u * cw -> H
#pragma unroll
  for (int h = 0; h < 2; h++) {
#pragma unroll
    for (int mf = 0; mf < 4; mf++) {
#pragma unroll
      for (int nf = 0; nf < 2; nf++) {
#pragma unroll
        for (int r = 0; r < 4; r++) {
          int row = m0 + wm * 128 + h * 64 + mf * 16 + quad * 4 + r;
          int col = n0 + wn * 32 + nf * 16 + lr;
          float g = gg[h][mf][nf][r];
          float u = uu[h][mf][nf][r];
          float s = (eidx >= 0) ? cw[(size_t)row * 8 + eidx] : 1.0f;
          float silu = g / (1.0f + __expf(-g));
          H[(size_t)row * 5120 + col] = f2b(s * silu * u);
        }
      }
    }
  }
}

// ---------------- down GEMM: Y[rows,1024] = H[rows,5120] @ Wd_cat (fp32 out) ----
__global__ __launch_bounds__(256) void gemm_down(
    const unsigned short* __restrict__ H,
    const unsigned short* __restrict__ WdTe,
    const unsigned short* __restrict__ WdTs,
    float* __restrict__ Y, int Mb) {
  __shared__ __align__(16) unsigned short lA[128 * 64];
  __shared__ __align__(16) unsigned short lB[64 * 64];
  const int tid = threadIdx.x;
  const int wid = tid >> 6, lane = tid & 63;
  const int lr = lane & 15, quad = lane >> 4;
  const int wm = wid >> 1, wn = wid & 1;
  int m_idx, n_idx;
  swizzle_mn(blockIdx.x, Mb, 16, m_idx, n_idx);
  const int m0 = m_idx * 128;
  const int n0 = n_idx * 64;

  floatx4 acc[4][2];
#pragma unroll
  for (int i = 0; i < 4; i++)
#pragma unroll
    for (int j = 0; j < 2; j++) acc[i][j] = (floatx4)0.f;

  for (int k0 = 0; k0 < 5120; k0 += 64) {
    __syncthreads();
#pragma unroll
    for (int i = 0; i < 4; i++) {
      int c = i * 256 + tid;
      int row = c >> 3;
      int g = ((c & 7) ^ (row & 7)) << 3;
      GLDS(H + (size_t)(m0 + row) * 5120 + k0 + g,
           lA + (size_t)(i * 256 + wid * 64) * 8);
    }
#pragma unroll
    for (int i = 0; i < 2; i++) {
      int c = i * 256 + tid;
      int row = c >> 3;
      int g = ((c & 7) ^ (row & 7)) << 3;
      const unsigned short* gpb;
      if (k0 < 4096) {
        gpb = WdTe + (size_t)(k0 >> 9) * (1024 * 512) +
              (size_t)(n0 + row) * 512 + (k0 & 511) + g;
      } else {
        gpb = WdTs + (size_t)(n0 + row) * 1024 + (k0 - 4096) + g;
      }
      GLDS(gpb, lB + (size_t)(i * 256 + wid * 64) * 8);
    }
    __syncthreads();
    bf16x8 af[4][2], bfr[2][2];
#pragma unroll
    for (int mt = 0; mt < 4; mt++) {
      int row = wm * 64 + mt * 16 + lr;
#pragma unroll
      for (int kt = 0; kt < 2; kt++)
        af[mt][kt] = *(const bf16x8*)(lA + row * 64 +
                                      ((((kt << 2) + quad) ^ (row & 7)) << 3));
    }
#pragma unroll
    for (int nt = 0; nt < 2; nt++) {
      int row = wn * 32 + nt * 16 + lr;
#pragma unroll
      for (int kt = 0; kt < 2; kt++)
        bfr[nt][kt] = *(const bf16x8*)(lB + row * 64 +
                                       ((((kt << 2) + quad) ^ (row & 7)) << 3));
    }
#pragma unroll
    for (int kt = 0; kt < 2; kt++)
#pragma unroll
      for (int mt = 0; mt < 4; mt++)
#pragma unroll
        for (int nt = 0; nt < 2; nt++)
          acc[mt][nt] = __builtin_amdgcn_mfma_f32_16x16x32_bf16(
              af[mt][kt], bfr[nt][kt], acc[mt][nt], 0, 0, 0);
  }

#pragma unroll
  for (int mt = 0; mt < 4; mt++)
#pragma unroll
    for (int nt = 0; nt < 2; nt++)
#pragma unroll
      for (int r = 0; r < 4; r++) {
        int row = m0 + wm * 64 + mt * 16 + quad * 4 + r;
        int col = n0 + wn * 32 + nt * 16 + lr;
        Y[(size_t)row * 1024 + col] = acc[mt][nt][r];
      }
}

extern "C" void kernel_launch(void* const* d_in, const int* in_sizes, int n_in,
                              void* d_out, int out_size, void* d_ws, size_t ws_size,
                              hipStream_t stream) {
  const float* hs  = (const float*)d_in[0];
  const float* rw  = (const float*)d_in[1];
  const float* wg  = (const float*)d_in[2];
  const float* wu  = (const float*)d_in[3];
  const float* wd  = (const float*)d_in[4];
  const float* wsg = (const float*)d_in[5];
  const float* wsu = (const float*)d_in[6];
  const float* wsd = (const float*)d_in[7];
  float* out = (float*)d_out;

  char* p = (char*)d_ws;
  float* cw = (float*)p;                    p += (size_t)4096 * 8 * 4;
  unsigned short* Xb   = (unsigned short*)p; p += (size_t)4096 * 1024 * 2;
  unsigned short* wgT  = (unsigned short*)p; p += (size_t)8 * 512 * 1024 * 2;
  unsigned short* wuT  = (unsigned short*)p; p += (size_t)8 * 512 * 1024 * 2;
  unsigned short* wsgT = (unsigned short*)p; p += (size_t)1024 * 1024 * 2;
  unsigned short* wsuT = (unsigned short*)p; p += (size_t)1024 * 1024 * 2;
  unsigned short* wdT  = (unsigned short*)p; p += (size_t)8 * 1024 * 512 * 2;
  unsigned short* wsdT = (unsigned short*)p; p += (size_t)1024 * 1024 * 2;
  unsigned short* GH   = (unsigned short*)p;
  const size_t base_bytes = (size_t)(p - (char*)d_ws);

  int chunks = 8;
  for (int c = 1; c <= 8; c *= 2) {
    size_t gh_bytes = ((size_t)4096 / c) * 5120 * 2;
    if (base_bytes + gh_bytes <= ws_size) { chunks = c; break; }
  }
  const int rows = 4096 / chunks;
  const int Mb = rows / 128;     // gemm_down 128-row tiles
  const int MbG = rows / 256;    // gemm_gu 256-row tiles

  dim3 tb(32, 8);
  cvt_f32_bf16<<<4096, 256, 0, stream>>>(hs, Xb);
  router_topk<<<4096, 64, 0, stream>>>(hs, rw, cw);
  transpose_f32_bf16_2<<<dim3(16, 32, 16), tb, 0, stream>>>(
      wg, wgT, 8, wu, wuT, 1024, 512);
  transpose_f32_bf16_2<<<dim3(32, 16, 8), tb, 0, stream>>>(
      wd, wdT, 8, wd, wdT, 512, 1024);
  transpose3_1024<<<dim3(32, 32, 3), tb, 0, stream>>>(
      wsg, wsu, wsd, wsgT, wsuT, wsdT);

  for (int c = 0; c < chunks; c++) {
    const unsigned short* Xc = Xb + (size_t)c * rows * 1024;
    const float* cwc = cw + (size_t)c * rows * 8;
    float* outc = out + (size_t)c * rows * 1024;
    gemm_gu_fused<<<MbG * 40, 512, 0, stream>>>(
        Xc, wgT, wsgT, wuT, wsuT, GH, cwc, MbG);
    gemm_down<<<Mb * 16, 256, 0, stream>>>(GH, wdT, wsdT, outc, Mb);
  }
}

// Round 2
// 292.833 us; speedup vs baseline: 1.0631x; 1.0584x over previous
//
#include <hip/hip_runtime.h>

typedef __attribute__((ext_vector_type(8))) short bf16x8;
typedef __attribute__((ext_vector_type(4))) float floatx4;

static __device__ __forceinline__ float b2f(unsigned short u) {
  union { unsigned int i; float f; } v; v.i = ((unsigned int)u) << 16; return v.f;
}
static __device__ __forceinline__ unsigned short f2b(float f) {
  union { float f; unsigned int i; } v; v.f = f;
  unsigned int x = v.i;
  return (unsigned short)((x + 0x7fffu + ((x >> 16) & 1u)) >> 16);
}

#define GLDS(gp, lp) \
  __builtin_amdgcn_global_load_lds( \
      (const __attribute__((address_space(1))) unsigned int*)(gp), \
      (__attribute__((address_space(3))) unsigned int*)(lp), 16, 0, 0)

static __device__ __forceinline__ void swizzle_mn(int lin, int Mb, int Nb,
                                                  int& m_idx, int& n_idx) {
  if ((Mb & 7) == 0) {
    int xcd = lin & 7;
    int idx = lin >> 3;
    int nstrips = Mb >> 3;
    m_idx = (idx % nstrips) * 8 + xcd;
    n_idx = idx / nstrips;
  } else {
    m_idx = lin % Mb;
    n_idx = lin / Mb;
  }
}

// ---------------- fp32 -> bf16 elementwise convert ------------------------------
__global__ void cvt_f32_bf16(const float* __restrict__ src,
                             unsigned short* __restrict__ dst) {
  int i = (blockIdx.x * 256 + threadIdx.x) * 4;
  float4 v = *(const float4*)(src + i);
  ushort4 o;
  o.x = f2b(v.x); o.y = f2b(v.y); o.z = f2b(v.z); o.w = f2b(v.w);
  *(ushort4*)(dst + i) = o;
}

// ------------- weight convert+transpose: fp32 [K,N] -> bf16 [N,K] ---------------
__global__ void transpose_f32_bf16_2(const float* __restrict__ sA,
                                     unsigned short* __restrict__ dA, int nzA,
                                     const float* __restrict__ sB,
                                     unsigned short* __restrict__ dB,
                                     int K, int N) {
  __shared__ unsigned short tile[32][33];
  int z = blockIdx.z;
  const float* src;
  unsigned short* dst;
  if (z < nzA) { src = sA + (size_t)z * K * N; dst = dA + (size_t)z * K * N; }
  else { src = sB + (size_t)(z - nzA) * K * N; dst = dB + (size_t)(z - nzA) * K * N; }
  const int bx = blockIdx.x * 32;
  const int by = blockIdx.y * 32;
  const int tx = threadIdx.x, ty = threadIdx.y;
#pragma unroll
  for (int i = 0; i < 4; i++)
    tile[ty + i * 8][tx] = f2b(src[(size_t)(by + ty + i * 8) * N + bx + tx]);
  __syncthreads();
#pragma unroll
  for (int i = 0; i < 4; i++)
    dst[(size_t)(bx + ty + i * 8) * K + by + tx] = tile[tx][ty + i * 8];
}

__global__ void transpose3_1024(const float* __restrict__ s0,
                                const float* __restrict__ s1,
                                const float* __restrict__ s2,
                                unsigned short* __restrict__ d0,
                                unsigned short* __restrict__ d1,
                                unsigned short* __restrict__ d2) {
  __shared__ unsigned short tile[32][33];
  const float* src = (blockIdx.z == 0) ? s0 : (blockIdx.z == 1) ? s1 : s2;
  unsigned short* dst = (blockIdx.z == 0) ? d0 : (blockIdx.z == 1) ? d1 : d2;
  const int bx = blockIdx.x * 32;
  const int by = blockIdx.y * 32;
  const int tx = threadIdx.x, ty = threadIdx.y;
#pragma unroll
  for (int i = 0; i < 4; i++)
    tile[ty + i * 8][tx] = f2b(src[(size_t)(by + ty + i * 8) * 1024 + bx + tx]);
  __syncthreads();
#pragma unroll
  for (int i = 0; i < 4; i++)
    dst[(size_t)(bx + ty + i * 8) * 1024 + by + tx] = tile[tx][ty + i * 8];
}

// ---------------- router: fp32 softmax over 8 logits, zero 2 smallest -----------
__global__ void router_topk(const float* __restrict__ X,
                            const float* __restrict__ RW,
                            float* __restrict__ cw) {
  const int t = blockIdx.x;
  const int lane = threadIdx.x;  // 64
  float acc[8];
#pragma unroll
  for (int e = 0; e < 8; e++) acc[e] = 0.f;
  for (int d = lane; d < 1024; d += 64) {
    float xv = X[(size_t)t * 1024 + d];
    const float* r = RW + d * 8;
    float4 r0 = *(const float4*)r;
    float4 r1 = *(const float4*)(r + 4);
    acc[0] += xv * r0.x; acc[1] += xv * r0.y;
    acc[2] += xv * r0.z; acc[3] += xv * r0.w;
    acc[4] += xv * r1.x; acc[5] += xv * r1.y;
    acc[6] += xv * r1.z; acc[7] += xv * r1.w;
  }
#pragma unroll
  for (int m = 1; m < 64; m <<= 1) {
#pragma unroll
    for (int e = 0; e < 8; e++) acc[e] += __shfl_xor(acc[e], m);
  }
  if (lane == 0) {
    float mx = acc[0];
#pragma unroll
    for (int e = 1; e < 8; e++) mx = fmaxf(mx, acc[e]);
    float prob[8], s = 0.f;
#pragma unroll
    for (int e = 0; e < 8; e++) { prob[e] = expf(acc[e] - mx); s += prob[e]; }
    float inv = 1.f / s;
#pragma unroll
    for (int e = 0; e < 8; e++) prob[e] *= inv;
    int m1 = 0;
#pragma unroll
    for (int e = 1; e < 8; e++) if (prob[e] < prob[m1]) m1 = e;
    int m2 = -1;
#pragma unroll
    for (int e = 0; e < 8; e++)
      if (e != m1 && (m2 < 0 || prob[e] < prob[m2])) m2 = e;
#pragma unroll
    for (int e = 0; e < 8; e++)
      cw[(size_t)t * 8 + e] = (e == m1 || e == m2) ? 0.f : prob[e];
  }
}

// ------------- fused gate+up GEMM: H = cw * silu(X@Wg) * (X@Wu) -----------------
// (unchanged from round 1: BM=256, BN=128, BK=64, 8 waves, dbuf 128KB LDS,
// 4 phases/K-tile, counted vmcnt(6), XOR swizzle, raw s_barrier, setprio.)
#define VMCNT(N) asm volatile("s_waitcnt vmcnt(" #N ")" ::: "memory")
#define BARS() do { __builtin_amdgcn_s_barrier(); \
                    __builtin_amdgcn_sched_barrier(0); } while (0)

#define STG_I0(K, BS) do { \
  GLDS(a0 + (K),          sm + (BS) + wid * 512); \
  GLDS(a0 + (K) + 131072, sm + (BS) + 8192 + wid * 512); } while (0)
#define STG_I1(K, BS) do { \
  GLDS(bg0 + (K),        sm + (BS) + 16384 + wid * 1024); \
  GLDS(bg0 + (K) + 8192, sm + (BS) + 16384 + wid * 1024 + 512); } while (0)
#define STG_I2(K, BS) do { \
  GLDS(bu0 + (K),        sm + (BS) + 24576 + wid * 1024); \
  GLDS(bu0 + (K) + 8192, sm + (BS) + 24576 + wid * 1024 + 512); } while (0)
#define STG_I3(K, BS) do { \
  GLDS(a0 + (K) + 65536,  sm + (BS) + 4096 + wid * 512); \
  GLDS(a0 + (K) + 196608, sm + (BS) + 12288 + wid * 512); } while (0)

#define READ_A(DST, DB, H) do { _Pragma("unroll") \
  for (int mf = 0; mf < 4; ++mf) { \
    const int row_ = wm * 128 + (H) * 64 + mf * 16 + lr; \
    const int rb_ = (DB) + row_ * 64; const int rx_ = row_ & 7; \
    DST[mf][0] = *(const bf16x8*)(sm + rb_ + ((quad ^ rx_) << 3)); \
    DST[mf][1] = *(const bf16x8*)(sm + rb_ + (((4 + quad) ^ rx_) << 3)); \
  } } while (0)

#define READ_B(DST, DB, RG) do { _Pragma("unroll") \
  for (int nf = 0; nf < 2; ++nf) { \
    const int row_ = wn * 32 + nf * 16 + lr; \
    const int rb_ = (DB) + (RG) + row_ * 64; const int rx_ = row_ & 7; \
    DST[nf][0] = *(const bf16x8*)(sm + rb_ + ((quad ^ rx_) << 3)); \
    DST[nf][1] = *(const bf16x8*)(sm + rb_ + (((4 + quad) ^ rx_) << 3)); \
  } } while (0)

#define MM(ACC, AF, BF) do { \
  __builtin_amdgcn_s_setprio(1); \
  _Pragma("unroll") \
  for (int mf = 0; mf < 4; ++mf) { _Pragma("unroll") \
    for (int nf = 0; nf < 2; ++nf) { \
      ACC[mf][nf] = __builtin_amdgcn_mfma_f32_16x16x32_bf16( \
          AF[mf][0], BF[nf][0], ACC[mf][nf], 0, 0, 0); \
      ACC[mf][nf] = __builtin_amdgcn_mfma_f32_16x16x32_bf16( \
          AF[mf][1], BF[nf][1], ACC[mf][nf], 0, 0, 0); \
    } } \
  __builtin_amdgcn_s_setprio(0); } while (0)

__global__ __launch_bounds__(512, 2) void gemm_gu_fused(
    const unsigned short* __restrict__ X,
    const unsigned short* __restrict__ WgTe,
    const unsigned short* __restrict__ WgTs,
    const unsigned short* __restrict__ WuTe,
    const unsigned short* __restrict__ WuTs,
    unsigned short* __restrict__ H,
    const float* __restrict__ cw, int Mb) {
  __shared__ __align__(16) unsigned short sm[65536];
  const int tid = threadIdx.x;
  const int wid = tid >> 6, lane = tid & 63;
  const int lr = lane & 15, quad = lane >> 4;
  const int wm = wid >> 2, wn = wid & 3;

  int m_idx, n_idx;
  {
    int lin = blockIdx.x;
    if ((Mb & 7) == 0) {
      int xcd = lin & 7, idx = lin >> 3;
      n_idx = idx % 40;
      m_idx = (idx / 40) * 8 + xcd;
    } else {
      m_idx = lin % Mb;
      n_idx = lin / Mb;
    }
  }
  const int m0 = m_idx * 256;
  const int n0 = n_idx * 128;

  const unsigned short *Bg, *Bu;
  int eidx = -1;
  if (n0 < 4096) {
    eidx = n0 >> 9;
    size_t off = ((size_t)eidx * 512 + (n0 & 511)) * 1024;
    Bg = WgTe + off; Bu = WuTe + off;
  } else {
    size_t off = (size_t)(n0 - 4096) * 1024;
    Bg = WgTs + off; Bu = WuTs + off;
  }

  const int grow8 = lane >> 3;
  const int gcol = ((lane & 7) ^ grow8) << 3;
  const unsigned short* a0 =
      X + (size_t)(m0 + wid * 8 + grow8) * 1024 + gcol;
  const unsigned short* bg0 =
      Bg + (size_t)(wid * 16 + grow8) * 1024 + gcol;
  const unsigned short* bu0 =
      Bu + (size_t)(wid * 16 + grow8) * 1024 + gcol;

  floatx4 gg[2][4][2], uu[2][4][2];
#pragma unroll
  for (int h = 0; h < 2; h++)
#pragma unroll
    for (int mf = 0; mf < 4; mf++)
#pragma unroll
      for (int nf = 0; nf < 2; nf++) {
        gg[h][mf][nf] = (floatx4)0.f;
        uu[h][mf][nf] = (floatx4)0.f;
      }

  bf16x8 fA0[4][2], fA1[4][2], fBg[2][2], fBu[2][2];

  STG_I0(0, 0); STG_I1(0, 0); STG_I2(0, 0); STG_I3(0, 0);

  for (int t = 0; t < 15; ++t) {
    const int db = (t & 1) << 15;
    const int nb = 32768 - db;
    const int kn = (t + 1) * 64;
    STG_I0(kn, nb);
    VMCNT(6); BARS();
    READ_A(fA0, db, 0);
    READ_B(fBg, db, 16384);
    MM(gg[0], fA0, fBg);
    STG_I1(kn, nb);
    VMCNT(6); BARS();
    READ_B(fBu, db, 24576);
    MM(uu[0], fA0, fBu);
    STG_I2(kn, nb);
    VMCNT(6); BARS();
    READ_A(fA1, db, 1);
    MM(gg[1], fA1, fBg);
    STG_I3(kn, nb);
    BARS();
    MM(uu[1], fA1, fBu);
  }
  {
    const int db = 32768;
    VMCNT(4); BARS();
    READ_A(fA0, db, 0);
    READ_B(fBg, db, 16384);
    MM(gg[0], fA0, fBg);
    VMCNT(2); BARS();
    READ_B(fBu, db, 24576);
    MM(uu[0], fA0, fBu);
    VMCNT(0); BARS();
    READ_A(fA1, db, 1);
    MM(gg[1], fA1, fBg);
    MM(uu[1], fA1, fBu);
  }

#pragma unroll
  for (int h = 0; h < 2; h++) {
#pragma unroll
    for (int mf = 0; mf < 4; mf++) {
#pragma unroll
      for (int nf = 0; nf < 2; nf++) {
#pragma unroll
        for (int r = 0; r < 4; r++) {
          int row = m0 + wm * 128 + h * 64 + mf * 16 + quad * 4 + r;
          int col = n0 + wn * 32 + nf * 16 + lr;
          float g = gg[h][mf][nf][r];
          float u = uu[h][mf][nf][r];
          float s = (eidx >= 0) ? cw[(size_t)row * 8 + eidx] : 1.0f;
          float silu = g / (1.0f + __expf(-g));
          H[(size_t)row * 5120 + col] = f2b(s * silu * u);
        }
      }
    }
  }
}

// ---------------- down GEMM: Y[rows,1024] = H[rows,5120] @ Wd_cat (fp32 out) ----
// NEW: triple-buffered pipeline. BM=128, BN=128, BK=64, 512 thr (8 waves 2Mx4N),
// grid = (rows/128) x 8 = 256 blocks (1/CU, single round). 96KB LDS = 3 x
// (A 16KB + B 16KB). Prefetch depth 2 K-tiles: tile t stages t+2; one
// vmcnt(4)+s_barrier per tile (vmcnt BEFORE barrier -> collective retire).
// XOR chunk-swizzle: pre-swizzled global src, linear GLDS dest, XOR ds_read.
#define DN_STG(KN, SBUF) do { \
  GLDS(Ha + (size_t)(KN),          smD + (SBUF) + wid * 512); \
  GLDS(Ha + (size_t)(KN) + 327680, smD + (SBUF) + 4096 + wid * 512); \
  const unsigned short *b0p_, *b1p_; \
  if ((KN) < 4096) { \
    const unsigned short* be_ = WdTe + ((size_t)((KN) >> 9)) * (1024 * 512) + ((KN) & 511); \
    b0p_ = be_ + (size_t)bn0 * 512 + gcol; \
    b1p_ = be_ + (size_t)(bn0 + 64) * 512 + gcol; \
  } else { \
    b0p_ = WdTs + (size_t)bn0 * 1024 + ((KN) - 4096) + gcol; \
    b1p_ = WdTs + (size_t)(bn0 + 64) * 1024 + ((KN) - 4096) + gcol; \
  } \
  GLDS(b0p_, smD + (SBUF) + 8192 + wid * 512); \
  GLDS(b1p_, smD + (SBUF) + 12288 + wid * 512); } while (0)

#define DN_TILE(T, BUF, SBUF, DOSTG, VM) do { \
  VMCNT(VM); BARS(); \
  if (DOSTG) { DN_STG(((T) + 2) * 64, SBUF); } \
  bf16x8 af_[4][2], bf_[2][2]; \
  _Pragma("unroll") \
  for (int mt = 0; mt < 4; ++mt) { \
    const int row_ = wm * 64 + mt * 16 + lr; \
    const int rb_ = (BUF) + row_ * 64; const int rx_ = row_ & 7; \
    af_[mt][0] = *(const bf16x8*)(smD + rb_ + ((quad ^ rx_) << 3)); \
    af_[mt][1] = *(const bf16x8*)(smD + rb_ + (((4 + quad) ^ rx_) << 3)); \
  } \
  _Pragma("unroll") \
  for (int nt = 0; nt < 2; ++nt) { \
    const int row_ = wn * 32 + nt * 16 + lr; \
    const int rb_ = (BUF) + 8192 + row_ * 64; const int rx_ = row_ & 7; \
    bf_[nt][0] = *(const bf16x8*)(smD + rb_ + ((quad ^ rx_) << 3)); \
    bf_[nt][1] = *(const bf16x8*)(smD + rb_ + (((4 + quad) ^ rx_) << 3)); \
  } \
  __builtin_amdgcn_s_setprio(1); \
  _Pragma("unroll") \
  for (int kt = 0; kt < 2; ++kt) \
    _Pragma("unroll") \
    for (int mt = 0; mt < 4; ++mt) \
      _Pragma("unroll") \
      for (int nt = 0; nt < 2; ++nt) \
        acc[mt][nt] = __builtin_amdgcn_mfma_f32_16x16x32_bf16( \
            af_[mt][kt], bf_[nt][kt], acc[mt][nt], 0, 0, 0); \
  __builtin_amdgcn_s_setprio(0); } while (0)

__global__ __launch_bounds__(512, 2) void gemm_down(
    const unsigned short* __restrict__ H,
    const unsigned short* __restrict__ WdTe,
    const unsigned short* __restrict__ WdTs,
    float* __restrict__ Y, int Mb) {
  // 3 buffers x 16384 shorts: per buffer A [0,8192), B [8192,16384)
  __shared__ __align__(16) unsigned short smD[49152];
  const int tid = threadIdx.x;
  const int wid = tid >> 6, lane = tid & 63;
  const int lr = lane & 15, quad = lane >> 4;
  const int wm = wid >> 2, wn = wid & 3;
  int m_idx, n_idx;
  swizzle_mn(blockIdx.x, Mb, 8, m_idx, n_idx);
  const int m0 = m_idx * 128;
  const int n0 = n_idx * 128;

  const int grow8 = lane >> 3;
  const int gcol = ((lane & 7) ^ grow8) << 3;
  const unsigned short* Ha = H + (size_t)(m0 + wid * 8 + grow8) * 5120 + gcol;
  const int bn0 = n0 + wid * 8 + grow8;

  floatx4 acc[4][2];
#pragma unroll
  for (int i = 0; i < 4; i++)
#pragma unroll
    for (int j = 0; j < 2; j++) acc[i][j] = (floatx4)0.f;

  // prologue: tiles 0,1 -> buffers 0,1
  DN_STG(0, 0);
  DN_STG(64, 16384);

  // 80 K-tiles total; main loop covers 0..77 (26 x 3), peel 78,79
  for (int t = 0; t < 78; t += 3) {
    DN_TILE(t,     0,     32768, true, 4);
    DN_TILE(t + 1, 16384, 0,     true, 4);
    DN_TILE(t + 2, 32768, 16384, true, 4);
  }
  DN_TILE(78, 0,     0, false, 4);
  DN_TILE(79, 16384, 0, false, 0);

#pragma unroll
  for (int mt = 0; mt < 4; mt++)
#pragma unroll
    for (int nt = 0; nt < 2; nt++)
#pragma unroll
      for (int r = 0; r < 4; r++) {
        int row = m0 + wm * 64 + mt * 16 + quad * 4 + r;
        int col = n0 + wn * 32 + nt * 16 + lr;
        Y[(size_t)row * 1024 + col] = acc[mt][nt][r];
      }
}

extern "C" void kernel_launch(void* const* d_in, const int* in_sizes, int n_in,
                              void* d_out, int out_size, void* d_ws, size_t ws_size,
                              hipStream_t stream) {
  const float* hs  = (const float*)d_in[0];
  const float* rw  = (const float*)d_in[1];
  const float* wg  = (const float*)d_in[2];
  const float* wu  = (const float*)d_in[3];
  const float* wd  = (const float*)d_in[4];
  const float* wsg = (const float*)d_in[5];
  const float* wsu = (const float*)d_in[6];
  const float* wsd = (const float*)d_in[7];
  float* out = (float*)d_out;

  char* p = (char*)d_ws;
  float* cw = (float*)p;                    p += (size_t)4096 * 8 * 4;
  unsigned short* Xb   = (unsigned short*)p; p += (size_t)4096 * 1024 * 2;
  unsigned short* wgT  = (unsigned short*)p; p += (size_t)8 * 512 * 1024 * 2;
  unsigned short* wuT  = (unsigned short*)p; p += (size_t)8 * 512 * 1024 * 2;
  unsigned short* wsgT = (unsigned short*)p; p += (size_t)1024 * 1024 * 2;
  unsigned short* wsuT = (unsigned short*)p; p += (size_t)1024 * 1024 * 2;
  unsigned short* wdT  = (unsigned short*)p; p += (size_t)8 * 1024 * 512 * 2;
  unsigned short* wsdT = (unsigned short*)p; p += (size_t)1024 * 1024 * 2;
  unsigned short* GH   = (unsigned short*)p;
  const size_t base_bytes = (size_t)(p - (char*)d_ws);

  int chunks = 8;
  for (int c = 1; c <= 8; c *= 2) {
    size_t gh_bytes = ((size_t)4096 / c) * 5120 * 2;
    if (base_bytes + gh_bytes <= ws_size) { chunks = c; break; }
  }
  const int rows = 4096 / chunks;
  const int Mb = rows / 128;     // gemm_down 128-row tiles
  const int MbG = rows / 256;    // gemm_gu 256-row tiles

  dim3 tb(32, 8);
  cvt_f32_bf16<<<4096, 256, 0, stream>>>(hs, Xb);
  router_topk<<<4096, 64, 0, stream>>>(hs, rw, cw);
  transpose_f32_bf16_2<<<dim3(16, 32, 16), tb, 0, stream>>>(
      wg, wgT, 8, wu, wuT, 1024, 512);
  transpose_f32_bf16_2<<<dim3(32, 16, 8), tb, 0, stream>>>(
      wd, wdT, 8, wd, wdT, 512, 1024);
  transpose3_1024<<<dim3(32, 32, 3), tb, 0, stream>>>(
      wsg, wsu, wsd, wsgT, wsuT, wsdT);

  for (int c = 0; c < chunks; c++) {
    const unsigned short* Xc = Xb + (size_t)c * rows * 1024;
    const float* cwc = cw + (size_t)c * rows * 8;
    float* outc = out + (size_t)c * rows * 1024;
    gemm_gu_fused<<<MbG * 40, 512, 0, stream>>>(
        Xc, wgT, wsgT, wuT, wsuT, GH, cwc, MbG);
    gemm_down<<<Mb * 8, 512, 0, stream>>>(GH, wdT, wsdT, outc, Mb);
  }
}

// Round 3
// 286.953 us; speedup vs baseline: 1.0849x; 1.0205x over previous
//
#include <hip/hip_runtime.h>

typedef __attribute__((ext_vector_type(8))) short bf16x8;
typedef __attribute__((ext_vector_type(8))) unsigned short ushort8;
typedef __attribute__((ext_vector_type(4))) float floatx4;

static __device__ __forceinline__ unsigned short f2b(float f) {
  union { float f; unsigned int i; } v; v.f = f;
  unsigned int x = v.i;
  return (unsigned short)((x + 0x7fffu + ((x >> 16) & 1u)) >> 16);
}

#define GLDS(gp, lp) \
  __builtin_amdgcn_global_load_lds( \
      (const __attribute__((address_space(1))) unsigned int*)(gp), \
      (__attribute__((address_space(3))) unsigned int*)(lp), 16, 0, 0)

static __device__ __forceinline__ void swizzle_mn(int lin, int Mb, int Nb,
                                                  int& m_idx, int& n_idx) {
  if ((Mb & 7) == 0) {
    int xcd = lin & 7;
    int idx = lin >> 3;
    int nstrips = Mb >> 3;
    m_idx = (idx % nstrips) * 8 + xcd;
    n_idx = idx / nstrips;
  } else {
    m_idx = lin % Mb;
    n_idx = lin / Mb;
  }
}

// -------- fused router + fp32->bf16 convert (one pass over hidden_states) ------
// 256 thr = 4 waves, wave per token. float4 loads, ushort4 bf16 stores.
__global__ __launch_bounds__(256) void router_cvt(
    const float* __restrict__ X, const float* __restrict__ RW,
    float* __restrict__ cw, unsigned short* __restrict__ Xb) {
  const int tid = threadIdx.x;
  const int wid = tid >> 6, lane = tid & 63;
  const int t = blockIdx.x * 4 + wid;
  const float* xp = X + (size_t)t * 1024;
  unsigned short* xo = Xb + (size_t)t * 1024;
  float acc[8];
#pragma unroll
  for (int e = 0; e < 8; e++) acc[e] = 0.f;
#pragma unroll
  for (int i = 0; i < 4; i++) {
    const int d0 = i * 256 + lane * 4;
    float4 v = *(const float4*)(xp + d0);
    ushort4 o;
    o.x = f2b(v.x); o.y = f2b(v.y); o.z = f2b(v.z); o.w = f2b(v.w);
    *(ushort4*)(xo + d0) = o;
    const float xv[4] = {v.x, v.y, v.z, v.w};
#pragma unroll
    for (int j = 0; j < 4; j++) {
      const float* r = RW + (size_t)(d0 + j) * 8;
      float4 r0 = *(const float4*)r;
      float4 r1 = *(const float4*)(r + 4);
      acc[0] += xv[j] * r0.x; acc[1] += xv[j] * r0.y;
      acc[2] += xv[j] * r0.z; acc[3] += xv[j] * r0.w;
      acc[4] += xv[j] * r1.x; acc[5] += xv[j] * r1.y;
      acc[6] += xv[j] * r1.z; acc[7] += xv[j] * r1.w;
    }
  }
#pragma unroll
  for (int m = 1; m < 64; m <<= 1) {
#pragma unroll
    for (int e = 0; e < 8; e++) acc[e] += __shfl_xor(acc[e], m);
  }
  if (lane == 0) {
    float mx = acc[0];
#pragma unroll
    for (int e = 1; e < 8; e++) mx = fmaxf(mx, acc[e]);
    float prob[8], s = 0.f;
#pragma unroll
    for (int e = 0; e < 8; e++) { prob[e] = expf(acc[e] - mx); s += prob[e]; }
    float inv = 1.f / s;
#pragma unroll
    for (int e = 0; e < 8; e++) prob[e] *= inv;
    int m1 = 0;
#pragma unroll
    for (int e = 1; e < 8; e++) if (prob[e] < prob[m1]) m1 = e;
    int m2 = -1;
#pragma unroll
    for (int e = 0; e < 8; e++)
      if (e != m1 && (m2 < 0 || prob[e] < prob[m2])) m2 = e;
#pragma unroll
    for (int e = 0; e < 8; e++)
      cw[(size_t)t * 8 + e] = (e == m1 || e == m2) ? 0.f : prob[e];
  }
}

// -------- all 27 weight transposes, one launch: fp32 [K,N] -> bf16 [N,K] --------
// 64x64 tile / 256 thr. float4 reads (16B/lane), LDS [k][n] rowstride 68,
// ds_write_b64 staging, ushort8 (16B/lane) global stores.
__global__ __launch_bounds__(256) void transpose_all(
    const float* __restrict__ wg, const float* __restrict__ wu,
    const float* __restrict__ wd, const float* __restrict__ wsg,
    const float* __restrict__ wsu, const float* __restrict__ wsd,
    unsigned short* __restrict__ wgT, unsigned short* __restrict__ wuT,
    unsigned short* __restrict__ wdT, unsigned short* __restrict__ wsgT,
    unsigned short* __restrict__ wsuT, unsigned short* __restrict__ wsdT) {
  __shared__ __align__(16) unsigned short T[64 * 68];
  const int z = blockIdx.z;
  const float* src; unsigned short* dst; int K, N;
  if (z < 8)       { src = wg  + (size_t)z * 1024 * 512;        dst = wgT + (size_t)z * 512 * 1024;        K = 1024; N = 512; }
  else if (z < 16) { src = wu  + (size_t)(z - 8) * 1024 * 512;  dst = wuT + (size_t)(z - 8) * 512 * 1024;  K = 1024; N = 512; }
  else if (z < 24) { src = wd  + (size_t)(z - 16) * 512 * 1024; dst = wdT + (size_t)(z - 16) * 1024 * 512; K = 512;  N = 1024; }
  else if (z == 24){ src = wsg; dst = wsgT; K = 1024; N = 1024; }
  else if (z == 25){ src = wsu; dst = wsuT; K = 1024; N = 1024; }
  else             { src = wsd; dst = wsdT; K = 1024; N = 1024; }
  const int bn = blockIdx.x * 64, bk = blockIdx.y * 64;
  if (bn >= N || bk >= K) return;
  const int tid = threadIdx.x;
  {
    const int r = tid >> 4;            // 0..15
    const int c = (tid & 15) * 4;      // 0..60
#pragma unroll
    for (int i = 0; i < 4; i++) {
      const int rr = r + i * 16;
      float4 v = *(const float4*)(src + (size_t)(bk + rr) * N + bn + c);
      ushort4 o;
      o.x = f2b(v.x); o.y = f2b(v.y); o.z = f2b(v.z); o.w = f2b(v.w);
      *(ushort4*)(&T[rr * 68 + c]) = o;
    }
  }
  __syncthreads();
  {
    const int n_ = tid >> 3;           // 0..31
    const int k0 = (tid & 7) * 8;      // 0..56
#pragma unroll
    for (int p = 0; p < 2; p++) {
      const int n = n_ + p * 32;
      ushort8 o;
#pragma unroll
      for (int j = 0; j < 8; j++) o[j] = T[(k0 + j) * 68 + n];
      *(ushort8*)(dst + (size_t)(bn + n) * K + bk + k0) = o;
    }
  }
}

// ------------- fused gate+up GEMM: H = cw * silu(X@Wg) * (X@Wu) -----------------
// (unchanged: BM=256, BN=128, BK=64, 8 waves, dbuf 128KB LDS, 4 phases/K-tile,
// counted vmcnt(6), XOR swizzle, raw s_barrier, setprio.)
#define VMCNT(N) asm volatile("s_waitcnt vmcnt(" #N ")" ::: "memory")
#define BARS() do { __builtin_amdgcn_s_barrier(); \
                    __builtin_amdgcn_sched_barrier(0); } while (0)

#define STG_I0(K, BS) do { \
  GLDS(a0 + (K),          sm + (BS) + wid * 512); \
  GLDS(a0 + (K) + 131072, sm + (BS) + 8192 + wid * 512); } while (0)
#define STG_I1(K, BS) do { \
  GLDS(bg0 + (K),        sm + (BS) + 16384 + wid * 1024); \
  GLDS(bg0 + (K) + 8192, sm + (BS) + 16384 + wid * 1024 + 512); } while (0)
#define STG_I2(K, BS) do { \
  GLDS(bu0 + (K),        sm + (BS) + 24576 + wid * 1024); \
  GLDS(bu0 + (K) + 8192, sm + (BS) + 24576 + wid * 1024 + 512); } while (0)
#define STG_I3(K, BS) do { \
  GLDS(a0 + (K) + 65536,  sm + (BS) + 4096 + wid * 512); \
  GLDS(a0 + (K) + 196608, sm + (BS) + 12288 + wid * 512); } while (0)

#define READ_A(DST, DB, H) do { _Pragma("unroll") \
  for (int mf = 0; mf < 4; ++mf) { \
    const int row_ = wm * 128 + (H) * 64 + mf * 16 + lr; \
    const int rb_ = (DB) + row_ * 64; const int rx_ = row_ & 7; \
    DST[mf][0] = *(const bf16x8*)(sm + rb_ + ((quad ^ rx_) << 3)); \
    DST[mf][1] = *(const bf16x8*)(sm + rb_ + (((4 + quad) ^ rx_) << 3)); \
  } } while (0)

#define READ_B(DST, DB, RG) do { _Pragma("unroll") \
  for (int nf = 0; nf < 2; ++nf) { \
    const int row_ = wn * 32 + nf * 16 + lr; \
    const int rb_ = (DB) + (RG) + row_ * 64; const int rx_ = row_ & 7; \
    DST[nf][0] = *(const bf16x8*)(sm + rb_ + ((quad ^ rx_) << 3)); \
    DST[nf][1] = *(const bf16x8*)(sm + rb_ + (((4 + quad) ^ rx_) << 3)); \
  } } while (0)

#define MM(ACC, AF, BF) do { \
  __builtin_amdgcn_s_setprio(1); \
  _Pragma("unroll") \
  for (int mf = 0; mf < 4; ++mf) { _Pragma("unroll") \
    for (int nf = 0; nf < 2; ++nf) { \
      ACC[mf][nf] = __builtin_amdgcn_mfma_f32_16x16x32_bf16( \
          AF[mf][0], BF[nf][0], ACC[mf][nf], 0, 0, 0); \
      ACC[mf][nf] = __builtin_amdgcn_mfma_f32_16x16x32_bf16( \
          AF[mf][1], BF[nf][1], ACC[mf][nf], 0, 0, 0); \
    } } \
  __builtin_amdgcn_s_setprio(0); } while (0)

__global__ __launch_bounds__(512, 2) void gemm_gu_fused(
    const unsigned short* __restrict__ X,
    const unsigned short* __restrict__ WgTe,
    const unsigned short* __restrict__ WgTs,
    const unsigned short* __restrict__ WuTe,
    const unsigned short* __restrict__ WuTs,
    unsigned short* __restrict__ H,
    const float* __restrict__ cw, int Mb) {
  __shared__ __align__(16) unsigned short sm[65536];
  const int tid = threadIdx.x;
  const int wid = tid >> 6, lane = tid & 63;
  const int lr = lane & 15, quad = lane >> 4;
  const int wm = wid >> 2, wn = wid & 3;

  int m_idx, n_idx;
  {
    int lin = blockIdx.x;
    if ((Mb & 7) == 0) {
      int xcd = lin & 7, idx = lin >> 3;
      n_idx = idx % 40;
      m_idx = (idx / 40) * 8 + xcd;
    } else {
      m_idx = lin % Mb;
      n_idx = lin / Mb;
    }
  }
  const int m0 = m_idx * 256;
  const int n0 = n_idx * 128;

  const unsigned short *Bg, *Bu;
  int eidx = -1;
  if (n0 < 4096) {
    eidx = n0 >> 9;
    size_t off = ((size_t)eidx * 512 + (n0 & 511)) * 1024;
    Bg = WgTe + off; Bu = WuTe + off;
  } else {
    size_t off = (size_t)(n0 - 4096) * 1024;
    Bg = WgTs + off; Bu = WuTs + off;
  }

  const int grow8 = lane >> 3;
  const int gcol = ((lane & 7) ^ grow8) << 3;
  const unsigned short* a0 =
      X + (size_t)(m0 + wid * 8 + grow8) * 1024 + gcol;
  const unsigned short* bg0 =
      Bg + (size_t)(wid * 16 + grow8) * 1024 + gcol;
  const unsigned short* bu0 =
      Bu + (size_t)(wid * 16 + grow8) * 1024 + gcol;

  floatx4 gg[2][4][2], uu[2][4][2];
#pragma unroll
  for (int h = 0; h < 2; h++)
#pragma unroll
    for (int mf = 0; mf < 4; mf++)
#pragma unroll
      for (int nf = 0; nf < 2; nf++) {
        gg[h][mf][nf] = (floatx4)0.f;
        uu[h][mf][nf] = (floatx4)0.f;
      }

  bf16x8 fA0[4][2], fA1[4][2], fBg[2][2], fBu[2][2];

  STG_I0(0, 0); STG_I1(0, 0); STG_I2(0, 0); STG_I3(0, 0);

  for (int t = 0; t < 15; ++t) {
    const int db = (t & 1) << 15;
    const int nb = 32768 - db;
    const int kn = (t + 1) * 64;
    STG_I0(kn, nb);
    VMCNT(6); BARS();
    READ_A(fA0, db, 0);
    READ_B(fBg, db, 16384);
    MM(gg[0], fA0, fBg);
    STG_I1(kn, nb);
    VMCNT(6); BARS();
    READ_B(fBu, db, 24576);
    MM(uu[0], fA0, fBu);
    STG_I2(kn, nb);
    VMCNT(6); BARS();
    READ_A(fA1, db, 1);
    MM(gg[1], fA1, fBg);
    STG_I3(kn, nb);
    BARS();
    MM(uu[1], fA1, fBu);
  }
  {
    const int db = 32768;
    VMCNT(4); BARS();
    READ_A(fA0, db, 0);
    READ_B(fBg, db, 16384);
    MM(gg[0], fA0, fBg);
    VMCNT(2); BARS();
    READ_B(fBu, db, 24576);
    MM(uu[0], fA0, fBu);
    VMCNT(0); BARS();
    READ_A(fA1, db, 1);
    MM(gg[1], fA1, fBg);
    MM(uu[1], fA1, fBu);
  }

#pragma unroll
  for (int h = 0; h < 2; h++) {
#pragma unroll
    for (int mf = 0; mf < 4; mf++) {
#pragma unroll
      for (int nf = 0; nf < 2; nf++) {
#pragma unroll
        for (int r = 0; r < 4; r++) {
          int row = m0 + wm * 128 + h * 64 + mf * 16 + quad * 4 + r;
          int col = n0 + wn * 32 + nf * 16 + lr;
          float g = gg[h][mf][nf][r];
          float u = uu[h][mf][nf][r];
          float s = (eidx >= 0) ? cw[(size_t)row * 8 + eidx] : 1.0f;
          float silu = g / (1.0f + __expf(-g));
          H[(size_t)row * 5120 + col] = f2b(s * silu * u);
        }
      }
    }
  }
}

// ---------------- down GEMM: Y[rows,1024] = H[rows,5120] @ Wd_cat (fp32 out) ----
// Quad-buffered pipeline, prefetch depth 3. BM=128, BN=128, BK=64, 512 thr
// (8 waves 2Mx4N), grid = (rows/128) x 8 = 256 blocks. 128KB LDS = 4 x
// (A 16KB + B 16KB). Tile t stages t+3; vmcnt(8) steady-state (before barrier),
// drain 8/8/4/0. XOR chunk-swizzle as in gu.
#define DN_STG(KN, SBUF) do { \
  GLDS(Ha + (size_t)(KN),          smD + (SBUF) + wid * 512); \
  GLDS(Ha + (size_t)(KN) + 327680, smD + (SBUF) + 4096 + wid * 512); \
  const unsigned short *b0p_, *b1p_; \
  if ((KN) < 4096) { \
    const unsigned short* be_ = WdTe + ((size_t)((KN) >> 9)) * (1024 * 512) + ((KN) & 511); \
    b0p_ = be_ + (size_t)bn0 * 512 + gcol; \
    b1p_ = be_ + (size_t)(bn0 + 64) * 512 + gcol; \
  } else { \
    b0p_ = WdTs + (size_t)bn0 * 1024 + ((KN) - 4096) + gcol; \
    b1p_ = WdTs + (size_t)(bn0 + 64) * 1024 + ((KN) - 4096) + gcol; \
  } \
  GLDS(b0p_, smD + (SBUF) + 8192 + wid * 512); \
  GLDS(b1p_, smD + (SBUF) + 12288 + wid * 512); } while (0)

#define DN_TILE(T, BUF, SBUF, DOSTG, VM) do { \
  VMCNT(VM); BARS(); \
  if (DOSTG) { DN_STG(((T) + 3) * 64, SBUF); } \
  bf16x8 af_[4][2], bf_[2][2]; \
  _Pragma("unroll") \
  for (int mt = 0; mt < 4; ++mt) { \
    const int row_ = wm * 64 + mt * 16 + lr; \
    const int rb_ = (BUF) + row_ * 64; const int rx_ = row_ & 7; \
    af_[mt][0] = *(const bf16x8*)(smD + rb_ + ((quad ^ rx_) << 3)); \
    af_[mt][1] = *(const bf16x8*)(smD + rb_ + (((4 + quad) ^ rx_) << 3)); \
  } \
  _Pragma("unroll") \
  for (int nt = 0; nt < 2; ++nt) { \
    const int row_ = wn * 32 + nt * 16 + lr; \
    const int rb_ = (BUF) + 8192 + row_ * 64; const int rx_ = row_ & 7; \
    bf_[nt][0] = *(const bf16x8*)(smD + rb_ + ((quad ^ rx_) << 3)); \
    bf_[nt][1] = *(const bf16x8*)(smD + rb_ + (((4 + quad) ^ rx_) << 3)); \
  } \
  __builtin_amdgcn_s_setprio(1); \
  _Pragma("unroll") \
  for (int kt = 0; kt < 2; ++kt) \
    _Pragma("unroll") \
    for (int mt = 0; mt < 4; ++mt) \
      _Pragma("unroll") \
      for (int nt = 0; nt < 2; ++nt) \
        acc[mt][nt] = __builtin_amdgcn_mfma_f32_16x16x32_bf16( \
            af_[mt][kt], bf_[nt][kt], acc[mt][nt], 0, 0, 0); \
  __builtin_amdgcn_s_setprio(0); } while (0)

__global__ __launch_bounds__(512, 2) void gemm_down(
    const unsigned short* __restrict__ H,
    const unsigned short* __restrict__ WdTe,
    const unsigned short* __restrict__ WdTs,
    float* __restrict__ Y, int Mb) {
  // 4 buffers x 16384 shorts: per buffer A [0,8192), B [8192,16384)
  __shared__ __align__(16) unsigned short smD[65536];
  const int tid = threadIdx.x;
  const int wid = tid >> 6, lane = tid & 63;
  const int lr = lane & 15, quad = lane >> 4;
  const int wm = wid >> 2, wn = wid & 3;
  int m_idx, n_idx;
  swizzle_mn(blockIdx.x, Mb, 8, m_idx, n_idx);
  const int m0 = m_idx * 128;
  const int n0 = n_idx * 128;

  const int grow8 = lane >> 3;
  const int gcol = ((lane & 7) ^ grow8) << 3;
  const unsigned short* Ha = H + (size_t)(m0 + wid * 8 + grow8) * 5120 + gcol;
  const int bn0 = n0 + wid * 8 + grow8;

  floatx4 acc[4][2];
#pragma unroll
  for (int i = 0; i < 4; i++)
#pragma unroll
    for (int j = 0; j < 2; j++) acc[i][j] = (floatx4)0.f;

  // prologue: tiles 0,1,2 -> buffers 0,1,2 (12 loads in flight)
  DN_STG(0, 0);
  DN_STG(64, 16384);
  DN_STG(128, 32768);

  // 80 K-tiles; main loop tiles 0..75 (19 x 4), staging t+3 (last stage = 78)
  for (int t = 0; t < 76; t += 4) {
    DN_TILE(t,     0,     49152, true, 8);
    DN_TILE(t + 1, 16384, 0,     true, 8);
    DN_TILE(t + 2, 32768, 16384, true, 8);
    DN_TILE(t + 3, 49152, 32768, true, 8);
  }
  // tail: 76 (stages 79), 77, 78, 79
  DN_TILE(76, 0,     49152, true,  8);
  DN_TILE(77, 16384, 0,     false, 8);
  DN_TILE(78, 32768, 0,     false, 4);
  DN_TILE(79, 49152, 0,     false, 0);

#pragma unroll
  for (int mt = 0; mt < 4; mt++)
#pragma unroll
    for (int nt = 0; nt < 2; nt++)
#pragma unroll
      for (int r = 0; r < 4; r++) {
        int row = m0 + wm * 64 + mt * 16 + quad * 4 + r;
        int col = n0 + wn * 32 + nt * 16 + lr;
        Y[(size_t)row * 1024 + col] = acc[mt][nt][r];
      }
}

extern "C" void kernel_launch(void* const* d_in, const int* in_sizes, int n_in,
                              void* d_out, int out_size, void* d_ws, size_t ws_size,
                              hipStream_t stream) {
  const float* hs  = (const float*)d_in[0];
  const float* rw  = (const float*)d_in[1];
  const float* wg  = (const float*)d_in[2];
  const float* wu  = (const float*)d_in[3];
  const float* wd  = (const float*)d_in[4];
  const float* wsg = (const float*)d_in[5];
  const float* wsu = (const float*)d_in[6];
  const float* wsd = (const float*)d_in[7];
  float* out = (float*)d_out;

  char* p = (char*)d_ws;
  float* cw = (float*)p;                    p += (size_t)4096 * 8 * 4;
  unsigned short* Xb   = (unsigned short*)p; p += (size_t)4096 * 1024 * 2;
  unsigned short* wgT  = (unsigned short*)p; p += (size_t)8 * 512 * 1024 * 2;
  unsigned short* wuT  = (unsigned short*)p; p += (size_t)8 * 512 * 1024 * 2;
  unsigned short* wsgT = (unsigned short*)p; p += (size_t)1024 * 1024 * 2;
  unsigned short* wsuT = (unsigned short*)p; p += (size_t)1024 * 1024 * 2;
  unsigned short* wdT  = (unsigned short*)p; p += (size_t)8 * 1024 * 512 * 2;
  unsigned short* wsdT = (unsigned short*)p; p += (size_t)1024 * 1024 * 2;
  unsigned short* GH   = (unsigned short*)p;
  const size_t base_bytes = (size_t)(p - (char*)d_ws);

  int chunks = 8;
  for (int c = 1; c <= 8; c *= 2) {
    size_t gh_bytes = ((size_t)4096 / c) * 5120 * 2;
    if (base_bytes + gh_bytes <= ws_size) { chunks = c; break; }
  }
  const int rows = 4096 / chunks;
  const int Mb = rows / 128;     // gemm_down 128-row tiles
  const int MbG = rows / 256;    // gemm_gu 256-row tiles

  router_cvt<<<1024, 256, 0, stream>>>(hs, rw, cw, Xb);
  transpose_all<<<dim3(16, 16, 27), 256, 0, stream>>>(
      wg, wu, wd, wsg, wsu, wsd, wgT, wuT, wdT, wsgT, wsuT, wsdT);

  for (int c = 0; c < chunks; c++) {
    const unsigned short* Xc = Xb + (size_t)c * rows * 1024;
    const float* cwc = cw + (size_t)c * rows * 8;
    float* outc = out + (size_t)c * rows * 1024;
    gemm_gu_fused<<<MbG * 40, 512, 0, stream>>>(
        Xc, wgT, wsgT, wuT, wsuT, GH, cwc, MbG);
    gemm_down<<<Mb * 8, 512, 0, stream>>>(GH, wdT, wsdT, outc, Mb);
  }
}